// Round 16
// baseline (242.474 us; speedup 1.0000x reference)
//
#include <hip/hip_runtime.h>
#include <math.h>

#define NODE_IN 64
#define NODE_OUT 96
#define EDGE_IN 16
#define EDGE_OUT 64
#define ACC_W 80          // NODE_IN + EDGE_IN
#define NB 500            // graphs
#define FPD 2048
#define FPE 128
#define XDIM 288          // 160 + 128
#define BN_EPS 1e-5f
#define HB 1024           // edges per hist/scatter block
#define NBLKP 512         // padded block count for transposed hist
#define NFPB 32           // fp tile blocks (32 rowgroups x 16 rows)

static __device__ __forceinline__ unsigned short f2bf(float f) {
    unsigned u = __float_as_uint(f);
    unsigned r = (u + 0x7fff + ((u >> 16) & 1)) >> 16;   // RN-even
    return (unsigned short)r;
}
static __device__ __forceinline__ float bflo(unsigned u) { return __uint_as_float(u << 16); }
static __device__ __forceinline__ float bfhi(unsigned u) { return __uint_as_float(u & 0xffff0000u); }

// ---------------- K1: hist | fp 16-row tile GEMM | nf->bf16 convert ----------
// fp: 32 blocks, 16 rows each; 1024 thr = 128 cols x 8 K-slices of 256.
// Raw per-slice partials to pfp[8][500][128] (no LDS) -> summed in colscan.
// W-traffic: 32 x 1 MB = 32 MB (was 131 MB).
__global__ __launch_bounds__(1024) void hist_fp_kernel(
    const int* __restrict__ dst, const int* __restrict__ gids,
    int* __restrict__ gkey, int* __restrict__ pbhT, int nblk,
    const float* __restrict__ fpv, const float* __restrict__ Wf,
    float* __restrict__ pfp,
    const float* __restrict__ nf, unsigned short* __restrict__ nfb,
    int nfTot, int E)
{
    __shared__ int h[NB];
    const int t = threadIdx.x;

    if (blockIdx.x >= nblk + NFPB) {
        // ---------------- nf -> bf16 conversion path ----------------
        const int b = blockIdx.x - nblk - NFPB;
        const size_t idx = ((size_t)b * 1024 + t) * 8;
        if (idx + 8 <= (size_t)nfTot) {
            const float4 a = *(const float4*)(nf + idx);
            const float4 c = *(const float4*)(nf + idx + 4);
            uint4 o;
            o.x = (unsigned)f2bf(a.x) | ((unsigned)f2bf(a.y) << 16);
            o.y = (unsigned)f2bf(a.z) | ((unsigned)f2bf(a.w) << 16);
            o.z = (unsigned)f2bf(c.x) | ((unsigned)f2bf(c.y) << 16);
            o.w = (unsigned)f2bf(c.z) | ((unsigned)f2bf(c.w) << 16);
            *(uint4*)(nfb + idx) = o;
        }
        return;
    }

    if (blockIdx.x >= nblk) {
        // ---------------- fp 16-row tile path ----------------
        const int rg = blockIdx.x - nblk;          // 0..31
        const int r0 = rg * 16;
        const int j  = t & 127;
        const int ks = __builtin_amdgcn_readfirstlane(t >> 7);  // 0..7
        const int k0 = ks * 256;

        const float* xp[16];
        #pragma unroll
        for (int r = 0; r < 16; ++r)
            xp[r] = fpv + (size_t)min(r0 + r, NB - 1) * FPD + k0;
        const float* __restrict__ wp = Wf + (size_t)k0 * FPE + j;

        float acc[16] = {};
        for (int k = 0; k < 256; k += 4) {
            #pragma unroll
            for (int u = 0; u < 4; ++u) {
                const float w = wp[(size_t)(k + u) * FPE];
                #pragma unroll
                for (int r = 0; r < 16; ++r)
                    acc[r] = fmaf(xp[r][k + u], w, acc[r]);
            }
        }
        float* __restrict__ pp = pfp + (size_t)ks * NB * FPE;
        #pragma unroll
        for (int r = 0; r < 16; ++r)
            if (r0 + r < NB) pp[(size_t)(r0 + r) * FPE + j] = acc[r];
        return;
    }

    // ---------------- histogram path ----------------
    for (int i = t; i < NB; i += 1024) h[i] = 0;
    __syncthreads();
    const int e = blockIdx.x * HB + t;
    if (e < E) {
        const int g = gids[dst[e]];
        gkey[e] = g;
        atomicAdd(&h[g], 1);
    }
    __syncthreads();
    for (int i = t; i < NB; i += 1024)
        pbhT[(size_t)i * NBLKP + blockIdx.x] = h[i];
}

// ---------------- K2: per-graph scan over blocks + fp finalize ---------------
__global__ __launch_bounds__(512) void colscan_kernel(
    const int* __restrict__ pbhT, int* __restrict__ pcs,
    int* __restrict__ gsum, int nblk,
    const float* __restrict__ pfp, const float* __restrict__ bf,
    const float* __restrict__ gam, const float* __restrict__ bet,
    const float* __restrict__ mu, const float* __restrict__ var,
    float* __restrict__ xbuf)
{
    __shared__ int s[512];
    const int g = blockIdx.x;
    const int t = threadIdx.x;
    const int v0 = (t < nblk) ? pbhT[(size_t)g * NBLKP + t] : 0;  // coalesced
    s[t] = v0;
    __syncthreads();
    for (int d = 1; d < 512; d <<= 1) {
        const int v = (t >= d) ? s[t - d] : 0;
        __syncthreads();
        s[t] += v;
        __syncthreads();
    }
    if (t < nblk) pcs[(size_t)t * NB + g] = s[t] - v0;  // scattered write
    if (t == 511) gsum[g] = s[511];

    // fp finalize: sum 8 K-slice partials, bias+BN+ReLU -> xbuf[:,160:288]
    if (t < FPE) {
        float a = 0.f;
        #pragma unroll
        for (int sl = 0; sl < 8; ++sl)
            a += pfp[((size_t)sl * NB + g) * FPE + t];
        const float sc = rsqrtf(var[t] + BN_EPS) * gam[t];
        const float sh = bet[t] - mu[t] * sc;
        xbuf[(size_t)g * XDIM + 160 + t] = fmaxf(fmaf(a + bf[t], sc, sh), 0.f);
    }
}

// ---------------- K3: scatter (src,eid) pairs; inline offs scan --------------
__global__ __launch_bounds__(1024) void scatter2_kernel(
    const int* __restrict__ gkey, const int* __restrict__ src,
    const int* __restrict__ pcs, const int* __restrict__ gsum,
    int2* __restrict__ sp, int* __restrict__ offs, int E)
{
    __shared__ int sc[512];
    __shared__ int offsL[NB];
    __shared__ int h[NB];
    __shared__ int basel[NB];
    const int t = threadIdx.x;

    int v0 = 0;
    if (t < 512) {
        v0 = (t < NB) ? gsum[t] : 0;
        sc[t] = v0;
    }
    __syncthreads();
    for (int d = 1; d < 512; d <<= 1) {
        int v = 0;
        if (t < 512 && t >= d) v = sc[t - d];
        __syncthreads();
        if (t < 512) sc[t] += v;
        __syncthreads();
    }
    if (t < NB) offsL[t] = sc[t] - v0;
    __syncthreads();

    for (int i = t; i < NB; i += 1024) {
        h[i] = 0;
        basel[i] = offsL[i] + pcs[(size_t)blockIdx.x * NB + i];  // coalesced read
    }
    if (blockIdx.x == 0 && t < NB) offs[t] = offsL[t];
    __syncthreads();

    const int e = blockIdx.x * HB + t;
    if (e < E) {
        const int g = gkey[e];
        const int r = atomicAdd(&h[g], 1);
        sp[basel[g] + r] = make_int2(src[e], e);   // one 8B scattered write
    }
}

// ---------------- K4: per-graph accumulation + mol GEMM + softmax ------------
__global__ __launch_bounds__(1024) void graph_accum(
    const int2* __restrict__ sp,
    const unsigned short* __restrict__ nfb, const float* __restrict__ ef,
    const int* __restrict__ offs, const int* __restrict__ tot,
    const float* __restrict__ Wm, const float* __restrict__ bm,
    const float* __restrict__ We, const float* __restrict__ be,
    float* __restrict__ xbuf, int E)
{
    const int g = blockIdx.x;
    const int t = threadIdx.x;
    const int lane = t & 63;
    const int w = t >> 6;            // 16 waves
    const int start = offs[g];
    const int cnt = tot[g];
    const int end = start + cnt;

    const uint4* __restrict__ nfb4 = (const uint4*)nfb;  // row s: 8 uint4 (64 bf16)
    const float4* __restrict__ ef4 = (const float4*)ef;  // row e: 4 float4

    __shared__ float sacc[16][ACC_W];
    __shared__ float accRow[ACC_W];
    __shared__ float red[1024];

    const int eidx  = lane >> 3;   // 0..7 (node: 8 edges per step)
    const int chunk = lane & 7;    // 0..7 (node: 8 bf16 = 16B per lane)
    const int eidx2 = lane >> 2;   // 0..15
    const int comp  = lane & 3;    // 0..3

    float nacc[8] = {};
    float eacc0 = 0.f, eacc1 = 0.f, eacc2 = 0.f, eacc3 = 0.f;

    for (int p0 = start + w * 64; p0 < end; p0 += 1024) {
        const int lim = min(64, end - p0);
        const int2 pr = sp[min(p0 + lane, E - 1)];
        const int sv = pr.x, ev = pr.y;

        #pragma unroll
        for (int r = 0; r < 2; ++r) {
            uint4 v[4];
            int ee[4];
            #pragma unroll
            for (int u = 0; u < 4; ++u) {
                ee[u] = (r * 4 + u) * 8 + eidx;
                const int s = __shfl(sv, ee[u]);
                v[u] = nfb4[(size_t)s * 8 + chunk];
            }
            #pragma unroll
            for (int u = 0; u < 4; ++u) {
                if (ee[u] < lim) {
                    nacc[0] += bflo(v[u].x); nacc[1] += bfhi(v[u].x);
                    nacc[2] += bflo(v[u].y); nacc[3] += bfhi(v[u].y);
                    nacc[4] += bflo(v[u].z); nacc[5] += bfhi(v[u].z);
                    nacc[6] += bflo(v[u].w); nacc[7] += bfhi(v[u].w);
                }
            }
        }

        {
            float4 v[4];
            int ee[4];
            #pragma unroll
            for (int u = 0; u < 4; ++u) {
                ee[u] = u * 16 + eidx2;
                const int eid = __shfl(ev, ee[u]);
                v[u] = ef4[(size_t)eid * 4 + comp];
            }
            #pragma unroll
            for (int u = 0; u < 4; ++u) {
                if (ee[u] < lim) {
                    eacc0 += v[u].x; eacc1 += v[u].y;
                    eacc2 += v[u].z; eacc3 += v[u].w;
                }
            }
        }
    }

    #pragma unroll
    for (int i = 0; i < 8; ++i) {
        nacc[i] += __shfl_xor(nacc[i], 8);
        nacc[i] += __shfl_xor(nacc[i], 16);
        nacc[i] += __shfl_xor(nacc[i], 32);
    }
    #pragma unroll
    for (int bit = 4; bit <= 32; bit <<= 1) {
        eacc0 += __shfl_xor(eacc0, bit);
        eacc1 += __shfl_xor(eacc1, bit);
        eacc2 += __shfl_xor(eacc2, bit);
        eacc3 += __shfl_xor(eacc3, bit);
    }
    if (lane < 8) {
        #pragma unroll
        for (int i = 0; i < 8; ++i)
            sacc[w][lane * 8 + i] = nacc[i];
    }
    if (lane < 4) {
        sacc[w][NODE_IN + lane * 4 + 0] = eacc0;
        sacc[w][NODE_IN + lane * 4 + 1] = eacc1;
        sacc[w][NODE_IN + lane * 4 + 2] = eacc2;
        sacc[w][NODE_IN + lane * 4 + 3] = eacc3;
    }
    __syncthreads();
    if (t < ACC_W) {
        float s = 0.f;
        #pragma unroll
        for (int w2 = 0; w2 < 16; ++w2) s += sacc[w2][t];
        accRow[t] = s;
    }
    __syncthreads();

    const float cntf = (float)cnt;
    float mr = 0.f;
    if (t < 96) {
        float m2 = 0.f;
        for (int k = 0; k < NODE_IN; ++k) m2 = fmaf(accRow[k], Wm[k * NODE_OUT + t], m2);
        mr = m2 + cntf * bm[t];
    } else if (t < 160) {
        const int j = t - 96;
        float m2 = 0.f;
        for (int k = 0; k < EDGE_IN; ++k) m2 = fmaf(accRow[NODE_IN + k], We[k * EDGE_OUT + j], m2);
        mr = m2 + cntf * be[j];
    }

    red[t] = (t < 160) ? mr : -1e30f;
    __syncthreads();
    for (int st = 512; st > 0; st >>= 1) {
        if (t < st) red[t] = fmaxf(red[t], red[t + st]);
        __syncthreads();
    }
    const float mx = red[0];
    __syncthreads();
    const float evx = (t < 160) ? expf(mr - mx) : 0.f;
    red[t] = evx;
    __syncthreads();
    for (int st = 512; st > 0; st >>= 1) {
        if (t < st) red[t] += red[t + st];
        __syncthreads();
    }
    if (t < 160) xbuf[(size_t)g * XDIM + t] = evx / red[0];
}

// ---------------- K5-K7: FFN, 16-row tiles + in-block split-K ----------------
// grid (32 rowgroups, NO/128 colgroups); 512 thr = 128 cols x 4 K-slices.
// W-traffic/layer = 32 x W_bytes (was 125 x).
template<int NO>
__global__ __launch_bounds__(512) void ffn_tile16(
    const float* __restrict__ X, const float* __restrict__ W,
    const float* __restrict__ bias, float* __restrict__ Y,
    int Ni, int doRelu)
{
    __shared__ float part[3][16][128];   // 24 KB
    const int t = threadIdx.x;
    const int col = t & 127;
    const int ks = __builtin_amdgcn_readfirstlane(t >> 7);  // 0..3
    const int r0 = blockIdx.x * 16;
    const int cg = blockIdx.y * 128 + col;
    const int kchunk = Ni >> 2;
    const int k0 = ks * kchunk;

    const float* xp[16];
    #pragma unroll
    for (int r = 0; r < 16; ++r)
        xp[r] = X + (size_t)min(r0 + r, NB - 1) * Ni + k0;
    const float* __restrict__ wp = W + (size_t)k0 * NO + cg;

    float acc[16] = {};
    for (int k = 0; k < kchunk; k += 4) {
        #pragma unroll
        for (int u = 0; u < 4; ++u) {
            const float w = wp[(size_t)(k + u) * NO];
            #pragma unroll
            for (int r = 0; r < 16; ++r)
                acc[r] = fmaf(xp[r][k + u], w, acc[r]);
        }
    }
    if (ks > 0) {
        #pragma unroll
        for (int r = 0; r < 16; ++r) part[ks - 1][r][col] = acc[r];
    }
    __syncthreads();
    if (ks == 0) {
        #pragma unroll
        for (int q = 0; q < 3; ++q)
            #pragma unroll
            for (int r = 0; r < 16; ++r) acc[r] += part[q][r][col];
        const float bv = bias[cg];
        #pragma unroll
        for (int r = 0; r < 16; ++r) {
            float o = acc[r] + bv;
            if (doRelu) o = fmaxf(o, 0.f);
            if (r0 + r < NB) Y[(size_t)(r0 + r) * NO + cg] = o;
        }
    }
}

extern "C" void kernel_launch(void* const* d_in, const int* in_sizes, int n_in,
                              void* d_out, int out_size, void* d_ws, size_t ws_size,
                              hipStream_t stream)
{
    const float* node_feats = (const float*)d_in[0];
    const float* edge_feats = (const float*)d_in[1];
    const float* fpv        = (const float*)d_in[2];
    const int*   src        = (const int*)d_in[3];
    const int*   dst        = (const int*)d_in[4];
    const int*   gids       = (const int*)d_in[5];
    const float* Wm  = (const float*)d_in[6];
    const float* bm  = (const float*)d_in[7];
    const float* We  = (const float*)d_in[8];
    const float* be  = (const float*)d_in[9];
    const float* Wf  = (const float*)d_in[10];
    const float* bf  = (const float*)d_in[11];
    const float* gam = (const float*)d_in[12];
    const float* bet = (const float*)d_in[13];
    const float* mu  = (const float*)d_in[14];
    const float* var = (const float*)d_in[15];
    const float* W0  = (const float*)d_in[16];
    const float* b0  = (const float*)d_in[17];
    const float* W1  = (const float*)d_in[18];
    const float* b1  = (const float*)d_in[19];
    const float* W2  = (const float*)d_in[20];
    const float* b2  = (const float*)d_in[21];
    const int E = in_sizes[3];
    const int nfTot = in_sizes[0];        // N * NODE_IN
    const int nblk = (E + HB - 1) / HB;   // 489 for E=500000 (must be <= 512)
    const int ncv = (nfTot / 8 + 1023) / 1024;   // conversion blocks

    // workspace layout (xbuf first: 500*288*4 B, 8B-aligned)
    float* xbuf  = (float*)d_ws;                          // [500][288]
    int2*  sp    = (int2*)(xbuf + (size_t)NB * XDIM);     // [E] (src, eid)
    int*   gkey  = (int*)(sp + E);                         // [E]
    int*   pbhT  = gkey + E;                               // [NB][NBLKP]
    int*   pcs   = pbhT + (size_t)NB * NBLKP;              // [nblk][NB]
    int*   gsum  = pcs + (size_t)nblk * NB;                // [NB]
    int*   offs  = gsum + NB;                              // [NB]
    float* pfp   = (float*)(offs + NB);                    // [8][500][128]
    float* h1    = pfp + (size_t)8 * NB * FPE;             // [500][512]
    float* h2    = h1 + (size_t)NB * 512;                  // [500][512]
    unsigned short* nfb = (unsigned short*)(h2 + (size_t)NB * 512);  // [N][64] bf16

    hipLaunchKernelGGL(hist_fp_kernel, dim3(nblk + NFPB + ncv), dim3(1024), 0, stream,
                       dst, gids, gkey, pbhT, nblk,
                       fpv, Wf, pfp, node_feats, nfb, nfTot, E);
    hipLaunchKernelGGL(colscan_kernel, dim3(NB), dim3(512), 0, stream,
                       pbhT, pcs, gsum, nblk,
                       pfp, bf, gam, bet, mu, var, xbuf);
    hipLaunchKernelGGL(scatter2_kernel, dim3(nblk), dim3(1024), 0, stream,
                       gkey, src, pcs, gsum, sp, offs, E);
    hipLaunchKernelGGL(graph_accum, dim3(NB), dim3(1024), 0, stream,
                       sp, nfb, edge_feats, offs, gsum,
                       Wm, bm, We, be, xbuf, E);
    hipLaunchKernelGGL((ffn_tile16<512>), dim3(32, 4), dim3(512), 0, stream,
                       xbuf, W0, b0, h1, XDIM, 1);
    hipLaunchKernelGGL((ffn_tile16<512>), dim3(32, 4), dim3(512), 0, stream,
                       h1, W1, b1, h2, 512, 1);
    hipLaunchKernelGGL((ffn_tile16<256>), dim3(32, 2), dim3(512), 0, stream,
                       h2, W2, b2, (float*)d_out, 512, 0);
}

// Round 17
// 100.515 us; speedup vs baseline: 2.4123x; 2.4123x over previous
//
#include <hip/hip_runtime.h>
#include <math.h>

#define NODE_IN 64
#define NODE_OUT 96
#define EDGE_IN 16
#define EDGE_OUT 64
#define ACC_W 80          // NODE_IN + EDGE_IN
#define NB 500            // graphs
#define FPD 2048
#define FPE 128
#define XDIM 288          // 160 + 128
#define BN_EPS 1e-5f
#define HB 1024           // edges per hist/scatter block
#define NBLKP 512         // padded block count for transposed hist

static __device__ __forceinline__ unsigned short f2bf(float f) {
    unsigned u = __float_as_uint(f);
    unsigned r = (u + 0x7fff + ((u >> 16) & 1)) >> 16;   // RN-even
    return (unsigned short)r;
}
static __device__ __forceinline__ float bflo(unsigned u) { return __uint_as_float(u << 16); }
static __device__ __forceinline__ float bfhi(unsigned u) { return __uint_as_float(u & 0xffff0000u); }

// ---------------- K1: hist | fp partial GEMM | nf->bf16 convert --------------
// (r15-proven form: fp = 500 blocks, 4 rows, 4 K-slices; no register blowup)
__global__ __launch_bounds__(1024) void hist_fp_kernel(
    const int* __restrict__ dst, const int* __restrict__ gids,
    int* __restrict__ gkey, int* __restrict__ pbhT, int nblk,
    const float* __restrict__ fpv, const float* __restrict__ Wf,
    float* __restrict__ pfp,
    const float* __restrict__ nf, unsigned short* __restrict__ nfb,
    int nfTot, int E)
{
    __shared__ int   h[NB];
    __shared__ float part[7][4][FPE];     // fp path, 14 KB
    const int t = threadIdx.x;

    if (blockIdx.x >= nblk + NB) {
        // ---------------- nf -> bf16 conversion path ----------------
        const int b = blockIdx.x - nblk - NB;
        const size_t idx = ((size_t)b * 1024 + t) * 8;
        if (idx + 8 <= (size_t)nfTot) {
            const float4 a = *(const float4*)(nf + idx);
            const float4 c = *(const float4*)(nf + idx + 4);
            uint4 o;
            o.x = (unsigned)f2bf(a.x) | ((unsigned)f2bf(a.y) << 16);
            o.y = (unsigned)f2bf(a.z) | ((unsigned)f2bf(a.w) << 16);
            o.z = (unsigned)f2bf(c.x) | ((unsigned)f2bf(c.y) << 16);
            o.w = (unsigned)f2bf(c.z) | ((unsigned)f2bf(c.w) << 16);
            *(uint4*)(nfb + idx) = o;
        }
        return;
    }

    if (blockIdx.x >= nblk) {
        // ---------------- fp partial path (4 rows, 4 K-slices) ----------------
        const int f   = blockIdx.x - nblk;   // 0..499
        const int rg  = f >> 2;              // 0..124
        const int ksl = f & 3;               // K-slice 0..3
        const int r0  = rg * 4;
        const int j   = t & 127;
        const int ks  = __builtin_amdgcn_readfirstlane(t >> 7);  // 0..7
        const int k0  = ksl * 512 + ks * 64;

        const float* __restrict__ xp0 = fpv + (size_t)(r0 + 0) * FPD + k0;
        const float* __restrict__ xp1 = fpv + (size_t)(r0 + 1) * FPD + k0;
        const float* __restrict__ xp2 = fpv + (size_t)(r0 + 2) * FPD + k0;
        const float* __restrict__ xp3 = fpv + (size_t)(r0 + 3) * FPD + k0;
        const float* __restrict__ wp  = Wf + (size_t)k0 * FPE + j;

        float a0 = 0.f, a1 = 0.f, a2 = 0.f, a3 = 0.f;
        for (int k = 0; k < 64; k += 8) {
            #pragma unroll
            for (int u = 0; u < 8; ++u) {
                const float w = wp[(size_t)(k + u) * FPE];
                a0 = fmaf(xp0[k + u], w, a0);
                a1 = fmaf(xp1[k + u], w, a1);
                a2 = fmaf(xp2[k + u], w, a2);
                a3 = fmaf(xp3[k + u], w, a3);
            }
        }
        if (ks > 0) {
            part[ks - 1][0][j] = a0; part[ks - 1][1][j] = a1;
            part[ks - 1][2][j] = a2; part[ks - 1][3][j] = a3;
        }
        __syncthreads();
        if (ks == 0) {
            #pragma unroll
            for (int qd = 0; qd < 7; ++qd) {
                a0 += part[qd][0][j]; a1 += part[qd][1][j];
                a2 += part[qd][2][j]; a3 += part[qd][3][j];
            }
            float* __restrict__ pp = pfp + ((size_t)ksl * NB + r0) * FPE + j;
            pp[0 * FPE] = a0; pp[1 * FPE] = a1;
            pp[2 * FPE] = a2; pp[3 * FPE] = a3;
        }
        return;
    }

    // ---------------- histogram path ----------------
    for (int i = t; i < NB; i += 1024) h[i] = 0;
    __syncthreads();
    const int e = blockIdx.x * HB + t;
    if (e < E) {
        const int g = gids[dst[e]];
        gkey[e] = g;
        atomicAdd(&h[g], 1);
    }
    __syncthreads();
    for (int i = t; i < NB; i += 1024)
        pbhT[(size_t)i * NBLKP + blockIdx.x] = h[i];
}

// ---------------- K2: per-graph scan over blocks + fp finalize ---------------
__global__ __launch_bounds__(512) void colscan_kernel(
    const int* __restrict__ pbhT, int* __restrict__ pcs,
    int* __restrict__ gsum, int nblk,
    const float* __restrict__ pfp, const float* __restrict__ bf,
    const float* __restrict__ gam, const float* __restrict__ bet,
    const float* __restrict__ mu, const float* __restrict__ var,
    float* __restrict__ xbuf)
{
    __shared__ int s[512];
    const int g = blockIdx.x;
    const int t = threadIdx.x;
    const int v0 = (t < nblk) ? pbhT[(size_t)g * NBLKP + t] : 0;  // coalesced
    s[t] = v0;
    __syncthreads();
    for (int d = 1; d < 512; d <<= 1) {
        const int v = (t >= d) ? s[t - d] : 0;
        __syncthreads();
        s[t] += v;
        __syncthreads();
    }
    if (t < nblk) pcs[(size_t)t * NB + g] = s[t] - v0;  // scattered write
    if (t == 511) gsum[g] = s[511];

    if (t < FPE) {
        const float a = (pfp[((size_t)0 * NB + g) * FPE + t] +
                         pfp[((size_t)1 * NB + g) * FPE + t]) +
                        (pfp[((size_t)2 * NB + g) * FPE + t] +
                         pfp[((size_t)3 * NB + g) * FPE + t]);
        const float sc = rsqrtf(var[t] + BN_EPS) * gam[t];
        const float sh = bet[t] - mu[t] * sc;
        xbuf[(size_t)g * XDIM + 160 + t] = fmaxf(fmaf(a + bf[t], sc, sh), 0.f);
    }
}

// ---------------- K3: scatter (src,eid) pairs; inline offs scan --------------
__global__ __launch_bounds__(1024) void scatter2_kernel(
    const int* __restrict__ gkey, const int* __restrict__ src,
    const int* __restrict__ pcs, const int* __restrict__ gsum,
    int2* __restrict__ sp, int* __restrict__ offs, int E)
{
    __shared__ int sc[512];
    __shared__ int offsL[NB];
    __shared__ int h[NB];
    __shared__ int basel[NB];
    const int t = threadIdx.x;

    int v0 = 0;
    if (t < 512) {
        v0 = (t < NB) ? gsum[t] : 0;
        sc[t] = v0;
    }
    __syncthreads();
    for (int d = 1; d < 512; d <<= 1) {
        int v = 0;
        if (t < 512 && t >= d) v = sc[t - d];
        __syncthreads();
        if (t < 512) sc[t] += v;
        __syncthreads();
    }
    if (t < NB) offsL[t] = sc[t] - v0;
    __syncthreads();

    for (int i = t; i < NB; i += 1024) {
        h[i] = 0;
        basel[i] = offsL[i] + pcs[(size_t)blockIdx.x * NB + i];  // coalesced read
    }
    if (blockIdx.x == 0 && t < NB) offs[t] = offsL[t];
    __syncthreads();

    const int e = blockIdx.x * HB + t;
    if (e < E) {
        const int g = gkey[e];
        const int r = atomicAdd(&h[g], 1);
        sp[basel[g] + r] = make_int2(src[e], e);   // one 8B scattered write
    }
}

// ---------------- K4: per-graph accumulation + mol GEMM + softmax ------------
__global__ __launch_bounds__(1024) void graph_accum(
    const int2* __restrict__ sp,
    const unsigned short* __restrict__ nfb, const float* __restrict__ ef,
    const int* __restrict__ offs, const int* __restrict__ tot,
    const float* __restrict__ Wm, const float* __restrict__ bm,
    const float* __restrict__ We, const float* __restrict__ be,
    float* __restrict__ xbuf, int E)
{
    const int g = blockIdx.x;
    const int t = threadIdx.x;
    const int lane = t & 63;
    const int w = t >> 6;            // 16 waves
    const int start = offs[g];
    const int cnt = tot[g];
    const int end = start + cnt;

    const uint4* __restrict__ nfb4 = (const uint4*)nfb;  // row s: 8 uint4 (64 bf16)
    const float4* __restrict__ ef4 = (const float4*)ef;  // row e: 4 float4

    __shared__ float sacc[16][ACC_W];
    __shared__ float accRow[ACC_W];
    __shared__ float red[1024];

    const int eidx  = lane >> 3;   // 0..7
    const int chunk = lane & 7;    // 0..7
    const int eidx2 = lane >> 2;   // 0..15
    const int comp  = lane & 3;    // 0..3

    float nacc[8] = {};
    float eacc0 = 0.f, eacc1 = 0.f, eacc2 = 0.f, eacc3 = 0.f;

    for (int p0 = start + w * 64; p0 < end; p0 += 1024) {
        const int lim = min(64, end - p0);
        const int2 pr = sp[min(p0 + lane, E - 1)];
        const int sv = pr.x, ev = pr.y;

        #pragma unroll
        for (int r = 0; r < 2; ++r) {
            uint4 v[4];
            int ee[4];
            #pragma unroll
            for (int u = 0; u < 4; ++u) {
                ee[u] = (r * 4 + u) * 8 + eidx;
                const int s = __shfl(sv, ee[u]);
                v[u] = nfb4[(size_t)s * 8 + chunk];
            }
            #pragma unroll
            for (int u = 0; u < 4; ++u) {
                if (ee[u] < lim) {
                    nacc[0] += bflo(v[u].x); nacc[1] += bfhi(v[u].x);
                    nacc[2] += bflo(v[u].y); nacc[3] += bfhi(v[u].y);
                    nacc[4] += bflo(v[u].z); nacc[5] += bfhi(v[u].z);
                    nacc[6] += bflo(v[u].w); nacc[7] += bfhi(v[u].w);
                }
            }
        }

        {
            float4 v[4];
            int ee[4];
            #pragma unroll
            for (int u = 0; u < 4; ++u) {
                ee[u] = u * 16 + eidx2;
                const int eid = __shfl(ev, ee[u]);
                v[u] = ef4[(size_t)eid * 4 + comp];
            }
            #pragma unroll
            for (int u = 0; u < 4; ++u) {
                if (ee[u] < lim) {
                    eacc0 += v[u].x; eacc1 += v[u].y;
                    eacc2 += v[u].z; eacc3 += v[u].w;
                }
            }
        }
    }

    #pragma unroll
    for (int i = 0; i < 8; ++i) {
        nacc[i] += __shfl_xor(nacc[i], 8);
        nacc[i] += __shfl_xor(nacc[i], 16);
        nacc[i] += __shfl_xor(nacc[i], 32);
    }
    #pragma unroll
    for (int bit = 4; bit <= 32; bit <<= 1) {
        eacc0 += __shfl_xor(eacc0, bit);
        eacc1 += __shfl_xor(eacc1, bit);
        eacc2 += __shfl_xor(eacc2, bit);
        eacc3 += __shfl_xor(eacc3, bit);
    }
    if (lane < 8) {
        #pragma unroll
        for (int i = 0; i < 8; ++i)
            sacc[w][lane * 8 + i] = nacc[i];
    }
    if (lane < 4) {
        sacc[w][NODE_IN + lane * 4 + 0] = eacc0;
        sacc[w][NODE_IN + lane * 4 + 1] = eacc1;
        sacc[w][NODE_IN + lane * 4 + 2] = eacc2;
        sacc[w][NODE_IN + lane * 4 + 3] = eacc3;
    }
    __syncthreads();
    if (t < ACC_W) {
        float s = 0.f;
        #pragma unroll
        for (int w2 = 0; w2 < 16; ++w2) s += sacc[w2][t];
        accRow[t] = s;
    }
    __syncthreads();

    const float cntf = (float)cnt;
    float mr = 0.f;
    if (t < 96) {
        float m2 = 0.f;
        for (int k = 0; k < NODE_IN; ++k) m2 = fmaf(accRow[k], Wm[k * NODE_OUT + t], m2);
        mr = m2 + cntf * bm[t];
    } else if (t < 160) {
        const int j = t - 96;
        float m2 = 0.f;
        for (int k = 0; k < EDGE_IN; ++k) m2 = fmaf(accRow[NODE_IN + k], We[k * EDGE_OUT + j], m2);
        mr = m2 + cntf * be[j];
    }

    red[t] = (t < 160) ? mr : -1e30f;
    __syncthreads();
    for (int st = 512; st > 0; st >>= 1) {
        if (t < st) red[t] = fmaxf(red[t], red[t + st]);
        __syncthreads();
    }
    const float mx = red[0];
    __syncthreads();
    const float evx = (t < 160) ? expf(mr - mx) : 0.f;
    red[t] = evx;
    __syncthreads();
    for (int st = 512; st > 0; st >>= 1) {
        if (t < st) red[t] += red[t + st];
        __syncthreads();
    }
    if (t < 160) xbuf[(size_t)g * XDIM + t] = evx / red[0];
}

// ---------------- K5-K7: FFN, 8-row tiles + split-K ---------------------------
// grid (63 rowgroups, NO/128 colgroups); 1024 thr = 128 cols x 8 K-slices.
// 8 accs + 8 row-ptrs per thread (safe VGPR); W-traffic/layer = 63 x W_bytes.
template<int NO>
__global__ __launch_bounds__(1024) void ffn_tile8(
    const float* __restrict__ X, const float* __restrict__ W,
    const float* __restrict__ bias, float* __restrict__ Y,
    int Ni, int doRelu)
{
    __shared__ float part[7][8][128];   // 28 KB
    const int t = threadIdx.x;
    const int col = t & 127;
    const int ks = __builtin_amdgcn_readfirstlane(t >> 7);  // 0..7
    const int r0 = blockIdx.x * 8;
    const int cg = blockIdx.y * 128 + col;
    const int kchunk = Ni >> 3;
    const int k0 = ks * kchunk;

    const float* __restrict__ xp0 = X + (size_t)min(r0 + 0, NB - 1) * Ni + k0;
    const float* __restrict__ xp1 = X + (size_t)min(r0 + 1, NB - 1) * Ni + k0;
    const float* __restrict__ xp2 = X + (size_t)min(r0 + 2, NB - 1) * Ni + k0;
    const float* __restrict__ xp3 = X + (size_t)min(r0 + 3, NB - 1) * Ni + k0;
    const float* __restrict__ xp4 = X + (size_t)min(r0 + 4, NB - 1) * Ni + k0;
    const float* __restrict__ xp5 = X + (size_t)min(r0 + 5, NB - 1) * Ni + k0;
    const float* __restrict__ xp6 = X + (size_t)min(r0 + 6, NB - 1) * Ni + k0;
    const float* __restrict__ xp7 = X + (size_t)min(r0 + 7, NB - 1) * Ni + k0;
    const float* __restrict__ wp  = W + (size_t)k0 * NO + cg;

    float a0 = 0.f, a1 = 0.f, a2 = 0.f, a3 = 0.f;
    float a4 = 0.f, a5 = 0.f, a6 = 0.f, a7 = 0.f;
    for (int k = 0; k < kchunk; k += 4) {
        #pragma unroll
        for (int u = 0; u < 4; ++u) {
            const float w = wp[(size_t)(k + u) * NO];
            a0 = fmaf(xp0[k + u], w, a0);
            a1 = fmaf(xp1[k + u], w, a1);
            a2 = fmaf(xp2[k + u], w, a2);
            a3 = fmaf(xp3[k + u], w, a3);
            a4 = fmaf(xp4[k + u], w, a4);
            a5 = fmaf(xp5[k + u], w, a5);
            a6 = fmaf(xp6[k + u], w, a6);
            a7 = fmaf(xp7[k + u], w, a7);
        }
    }
    if (ks > 0) {
        part[ks - 1][0][col] = a0; part[ks - 1][1][col] = a1;
        part[ks - 1][2][col] = a2; part[ks - 1][3][col] = a3;
        part[ks - 1][4][col] = a4; part[ks - 1][5][col] = a5;
        part[ks - 1][6][col] = a6; part[ks - 1][7][col] = a7;
    }
    __syncthreads();
    if (ks == 0) {
        #pragma unroll
        for (int q = 0; q < 7; ++q) {
            a0 += part[q][0][col]; a1 += part[q][1][col];
            a2 += part[q][2][col]; a3 += part[q][3][col];
            a4 += part[q][4][col]; a5 += part[q][5][col];
            a6 += part[q][6][col]; a7 += part[q][7][col];
        }
        const float bv = bias[cg];
        float o[8] = {a0 + bv, a1 + bv, a2 + bv, a3 + bv,
                      a4 + bv, a5 + bv, a6 + bv, a7 + bv};
        #pragma unroll
        for (int r = 0; r < 8; ++r) {
            if (doRelu) o[r] = fmaxf(o[r], 0.f);
            if (r0 + r < NB) Y[(size_t)(r0 + r) * NO + cg] = o[r];
        }
    }
}

extern "C" void kernel_launch(void* const* d_in, const int* in_sizes, int n_in,
                              void* d_out, int out_size, void* d_ws, size_t ws_size,
                              hipStream_t stream)
{
    const float* node_feats = (const float*)d_in[0];
    const float* edge_feats = (const float*)d_in[1];
    const float* fpv        = (const float*)d_in[2];
    const int*   src        = (const int*)d_in[3];
    const int*   dst        = (const int*)d_in[4];
    const int*   gids       = (const int*)d_in[5];
    const float* Wm  = (const float*)d_in[6];
    const float* bm  = (const float*)d_in[7];
    const float* We  = (const float*)d_in[8];
    const float* be  = (const float*)d_in[9];
    const float* Wf  = (const float*)d_in[10];
    const float* bf  = (const float*)d_in[11];
    const float* gam = (const float*)d_in[12];
    const float* bet = (const float*)d_in[13];
    const float* mu  = (const float*)d_in[14];
    const float* var = (const float*)d_in[15];
    const float* W0  = (const float*)d_in[16];
    const float* b0  = (const float*)d_in[17];
    const float* W1  = (const float*)d_in[18];
    const float* b1  = (const float*)d_in[19];
    const float* W2  = (const float*)d_in[20];
    const float* b2  = (const float*)d_in[21];
    const int E = in_sizes[3];
    const int nfTot = in_sizes[0];        // N * NODE_IN
    const int nblk = (E + HB - 1) / HB;   // 489 for E=500000 (must be <= 512)
    const int ncv = (nfTot / 8 + 1023) / 1024;   // conversion blocks

    // workspace layout (xbuf first: 500*288*4 B, 8B-aligned)
    float* xbuf  = (float*)d_ws;                          // [500][288]
    int2*  sp    = (int2*)(xbuf + (size_t)NB * XDIM);     // [E] (src, eid)
    int*   gkey  = (int*)(sp + E);                         // [E]
    int*   pbhT  = gkey + E;                               // [NB][NBLKP]
    int*   pcs   = pbhT + (size_t)NB * NBLKP;              // [nblk][NB]
    int*   gsum  = pcs + (size_t)nblk * NB;                // [NB]
    int*   offs  = gsum + NB;                              // [NB]
    float* pfp   = (float*)(offs + NB);                    // [4][500][128]
    float* h1    = pfp + (size_t)4 * NB * FPE;             // [500][512]
    float* h2    = h1 + (size_t)NB * 512;                  // [500][512]
    unsigned short* nfb = (unsigned short*)(h2 + (size_t)NB * 512);  // [N][64] bf16

    hipLaunchKernelGGL(hist_fp_kernel, dim3(nblk + NB + ncv), dim3(1024), 0, stream,
                       dst, gids, gkey, pbhT, nblk,
                       fpv, Wf, pfp, node_feats, nfb, nfTot, E);
    hipLaunchKernelGGL(colscan_kernel, dim3(NB), dim3(512), 0, stream,
                       pbhT, pcs, gsum, nblk,
                       pfp, bf, gam, bet, mu, var, xbuf);
    hipLaunchKernelGGL(scatter2_kernel, dim3(nblk), dim3(1024), 0, stream,
                       gkey, src, pcs, gsum, sp, offs, E);
    hipLaunchKernelGGL(graph_accum, dim3(NB), dim3(1024), 0, stream,
                       sp, nfb, edge_feats, offs, gsum,
                       Wm, bm, We, be, xbuf, E);
    hipLaunchKernelGGL((ffn_tile8<512>), dim3(63, 4), dim3(1024), 0, stream,
                       xbuf, W0, b0, h1, XDIM, 1);
    hipLaunchKernelGGL((ffn_tile8<512>), dim3(63, 4), dim3(1024), 0, stream,
                       h1, W1, b1, h2, 512, 1);
    hipLaunchKernelGGL((ffn_tile8<256>), dim3(63, 2), dim3(1024), 0, stream,
                       h2, W2, b2, (float*)d_out, 512, 0);
}

// Round 18
// 92.655 us; speedup vs baseline: 2.6170x; 1.0848x over previous
//
#include <hip/hip_runtime.h>
#include <math.h>

#define NODE_IN 64
#define NODE_OUT 96
#define EDGE_IN 16
#define EDGE_OUT 64
#define ACC_W 80          // NODE_IN + EDGE_IN
#define NB 500            // graphs
#define FPD 2048
#define FPE 128
#define XDIM 288          // 160 + 128
#define BN_EPS 1e-5f
#define HB 1024           // edges per hist/scatter block
#define NBLKP 512         // padded block count for transposed hist

static __device__ __forceinline__ unsigned short f2bf(float f) {
    unsigned u = __float_as_uint(f);
    unsigned r = (u + 0x7fff + ((u >> 16) & 1)) >> 16;   // RN-even
    return (unsigned short)r;
}
static __device__ __forceinline__ float bflo(unsigned u) { return __uint_as_float(u << 16); }
static __device__ __forceinline__ float bfhi(unsigned u) { return __uint_as_float(u & 0xffff0000u); }

// ---------------- K1: hist | fp partial GEMM | nf->bf16 convert --------------
__global__ __launch_bounds__(1024) void hist_fp_kernel(
    const int* __restrict__ dst, const int* __restrict__ gids,
    int* __restrict__ gkey, int* __restrict__ pbhT, int nblk,
    const float* __restrict__ fpv, const float* __restrict__ Wf,
    float* __restrict__ pfp,
    const float* __restrict__ nf, unsigned short* __restrict__ nfb,
    int nfTot, int E)
{
    __shared__ int   h[NB];
    __shared__ float part[7][4][FPE];     // fp path, 14 KB
    const int t = threadIdx.x;

    if (blockIdx.x >= nblk + NB) {
        // ---------------- nf -> bf16 conversion path ----------------
        const int b = blockIdx.x - nblk - NB;
        const size_t idx = ((size_t)b * 1024 + t) * 8;
        if (idx + 8 <= (size_t)nfTot) {
            const float4 a = *(const float4*)(nf + idx);
            const float4 c = *(const float4*)(nf + idx + 4);
            uint4 o;
            o.x = (unsigned)f2bf(a.x) | ((unsigned)f2bf(a.y) << 16);
            o.y = (unsigned)f2bf(a.z) | ((unsigned)f2bf(a.w) << 16);
            o.z = (unsigned)f2bf(c.x) | ((unsigned)f2bf(c.y) << 16);
            o.w = (unsigned)f2bf(c.z) | ((unsigned)f2bf(c.w) << 16);
            *(uint4*)(nfb + idx) = o;
        }
        return;
    }

    if (blockIdx.x >= nblk) {
        // ---------------- fp partial path (4 rows, 4 K-slices) ----------------
        const int f   = blockIdx.x - nblk;   // 0..499
        const int rg  = f >> 2;              // 0..124
        const int ksl = f & 3;               // K-slice 0..3
        const int r0  = rg * 4;
        const int j   = t & 127;
        const int ks  = __builtin_amdgcn_readfirstlane(t >> 7);  // 0..7
        const int k0  = ksl * 512 + ks * 64;

        const float* __restrict__ xp0 = fpv + (size_t)(r0 + 0) * FPD + k0;
        const float* __restrict__ xp1 = fpv + (size_t)(r0 + 1) * FPD + k0;
        const float* __restrict__ xp2 = fpv + (size_t)(r0 + 2) * FPD + k0;
        const float* __restrict__ xp3 = fpv + (size_t)(r0 + 3) * FPD + k0;
        const float* __restrict__ wp  = Wf + (size_t)k0 * FPE + j;

        float a0 = 0.f, a1 = 0.f, a2 = 0.f, a3 = 0.f;
        for (int k = 0; k < 64; k += 8) {
            #pragma unroll
            for (int u = 0; u < 8; ++u) {
                const float w = wp[(size_t)(k + u) * FPE];
                a0 = fmaf(xp0[k + u], w, a0);
                a1 = fmaf(xp1[k + u], w, a1);
                a2 = fmaf(xp2[k + u], w, a2);
                a3 = fmaf(xp3[k + u], w, a3);
            }
        }
        if (ks > 0) {
            part[ks - 1][0][j] = a0; part[ks - 1][1][j] = a1;
            part[ks - 1][2][j] = a2; part[ks - 1][3][j] = a3;
        }
        __syncthreads();
        if (ks == 0) {
            #pragma unroll
            for (int qd = 0; qd < 7; ++qd) {
                a0 += part[qd][0][j]; a1 += part[qd][1][j];
                a2 += part[qd][2][j]; a3 += part[qd][3][j];
            }
            float* __restrict__ pp = pfp + ((size_t)ksl * NB + r0) * FPE + j;
            pp[0 * FPE] = a0; pp[1 * FPE] = a1;
            pp[2 * FPE] = a2; pp[3 * FPE] = a3;
        }
        return;
    }

    // ---------------- histogram path ----------------
    for (int i = t; i < NB; i += 1024) h[i] = 0;
    __syncthreads();
    const int e = blockIdx.x * HB + t;
    if (e < E) {
        const int g = gids[dst[e]];
        gkey[e] = g;
        atomicAdd(&h[g], 1);
    }
    __syncthreads();
    for (int i = t; i < NB; i += 1024)
        pbhT[(size_t)i * NBLKP + blockIdx.x] = h[i];
}

// ---------------- K2: per-graph scan over blocks + fp finalize ---------------
__global__ __launch_bounds__(512) void colscan_kernel(
    const int* __restrict__ pbhT, int* __restrict__ pcs,
    int* __restrict__ gsum, int nblk,
    const float* __restrict__ pfp, const float* __restrict__ bf,
    const float* __restrict__ gam, const float* __restrict__ bet,
    const float* __restrict__ mu, const float* __restrict__ var,
    float* __restrict__ xbuf)
{
    __shared__ int s[512];
    const int g = blockIdx.x;
    const int t = threadIdx.x;
    const int v0 = (t < nblk) ? pbhT[(size_t)g * NBLKP + t] : 0;  // coalesced
    s[t] = v0;
    __syncthreads();
    for (int d = 1; d < 512; d <<= 1) {
        const int v = (t >= d) ? s[t - d] : 0;
        __syncthreads();
        s[t] += v;
        __syncthreads();
    }
    if (t < nblk) pcs[(size_t)t * NB + g] = s[t] - v0;  // scattered write
    if (t == 511) gsum[g] = s[511];

    if (t < FPE) {
        const float a = (pfp[((size_t)0 * NB + g) * FPE + t] +
                         pfp[((size_t)1 * NB + g) * FPE + t]) +
                        (pfp[((size_t)2 * NB + g) * FPE + t] +
                         pfp[((size_t)3 * NB + g) * FPE + t]);
        const float sc = rsqrtf(var[t] + BN_EPS) * gam[t];
        const float sh = bet[t] - mu[t] * sc;
        xbuf[(size_t)g * XDIM + 160 + t] = fmaxf(fmaf(a + bf[t], sc, sh), 0.f);
    }
}

// ---------------- K3: scatter (src,eid) pairs; inline offs scan --------------
__global__ __launch_bounds__(1024) void scatter2_kernel(
    const int* __restrict__ gkey, const int* __restrict__ src,
    const int* __restrict__ pcs, const int* __restrict__ gsum,
    int2* __restrict__ sp, int* __restrict__ offs, int E)
{
    __shared__ int sc[512];
    __shared__ int offsL[NB];
    __shared__ int h[NB];
    __shared__ int basel[NB];
    const int t = threadIdx.x;

    int v0 = 0;
    if (t < 512) {
        v0 = (t < NB) ? gsum[t] : 0;
        sc[t] = v0;
    }
    __syncthreads();
    for (int d = 1; d < 512; d <<= 1) {
        int v = 0;
        if (t < 512 && t >= d) v = sc[t - d];
        __syncthreads();
        if (t < 512) sc[t] += v;
        __syncthreads();
    }
    if (t < NB) offsL[t] = sc[t] - v0;
    __syncthreads();

    for (int i = t; i < NB; i += 1024) {
        h[i] = 0;
        basel[i] = offsL[i] + pcs[(size_t)blockIdx.x * NB + i];  // coalesced read
    }
    if (blockIdx.x == 0 && t < NB) offs[t] = offsL[t];
    __syncthreads();

    const int e = blockIdx.x * HB + t;
    if (e < E) {
        const int g = gkey[e];
        const int r = atomicAdd(&h[g], 1);
        sp[basel[g] + r] = make_int2(src[e], e);   // one 8B scattered write
    }
}

// ---------------- K4: per-graph accumulation + mol GEMM + softmax ------------
__global__ __launch_bounds__(1024) void graph_accum(
    const int2* __restrict__ sp,
    const unsigned short* __restrict__ nfb, const float* __restrict__ ef,
    const int* __restrict__ offs, const int* __restrict__ tot,
    const float* __restrict__ Wm, const float* __restrict__ bm,
    const float* __restrict__ We, const float* __restrict__ be,
    float* __restrict__ xbuf, int E)
{
    const int g = blockIdx.x;
    const int t = threadIdx.x;
    const int lane = t & 63;
    const int w = t >> 6;            // 16 waves
    const int start = offs[g];
    const int cnt = tot[g];
    const int end = start + cnt;

    const uint4* __restrict__ nfb4 = (const uint4*)nfb;  // row s: 8 uint4 (64 bf16)
    const float4* __restrict__ ef4 = (const float4*)ef;  // row e: 4 float4

    __shared__ float sacc[16][ACC_W];
    __shared__ float accRow[ACC_W];
    __shared__ float red[1024];

    const int eidx  = lane >> 3;   // 0..7
    const int chunk = lane & 7;    // 0..7
    const int eidx2 = lane >> 2;   // 0..15
    const int comp  = lane & 3;    // 0..3

    float nacc[8] = {};
    float eacc0 = 0.f, eacc1 = 0.f, eacc2 = 0.f, eacc3 = 0.f;

    for (int p0 = start + w * 64; p0 < end; p0 += 1024) {
        const int lim = min(64, end - p0);
        const int2 pr = sp[min(p0 + lane, E - 1)];
        const int sv = pr.x, ev = pr.y;

        #pragma unroll
        for (int r = 0; r < 2; ++r) {
            uint4 v[4];
            int ee[4];
            #pragma unroll
            for (int u = 0; u < 4; ++u) {
                ee[u] = (r * 4 + u) * 8 + eidx;
                const int s = __shfl(sv, ee[u]);
                v[u] = nfb4[(size_t)s * 8 + chunk];
            }
            #pragma unroll
            for (int u = 0; u < 4; ++u) {
                if (ee[u] < lim) {
                    nacc[0] += bflo(v[u].x); nacc[1] += bfhi(v[u].x);
                    nacc[2] += bflo(v[u].y); nacc[3] += bfhi(v[u].y);
                    nacc[4] += bflo(v[u].z); nacc[5] += bfhi(v[u].z);
                    nacc[6] += bflo(v[u].w); nacc[7] += bfhi(v[u].w);
                }
            }
        }

        {
            float4 v[4];
            int ee[4];
            #pragma unroll
            for (int u = 0; u < 4; ++u) {
                ee[u] = u * 16 + eidx2;
                const int eid = __shfl(ev, ee[u]);
                v[u] = ef4[(size_t)eid * 4 + comp];
            }
            #pragma unroll
            for (int u = 0; u < 4; ++u) {
                if (ee[u] < lim) {
                    eacc0 += v[u].x; eacc1 += v[u].y;
                    eacc2 += v[u].z; eacc3 += v[u].w;
                }
            }
        }
    }

    #pragma unroll
    for (int i = 0; i < 8; ++i) {
        nacc[i] += __shfl_xor(nacc[i], 8);
        nacc[i] += __shfl_xor(nacc[i], 16);
        nacc[i] += __shfl_xor(nacc[i], 32);
    }
    #pragma unroll
    for (int bit = 4; bit <= 32; bit <<= 1) {
        eacc0 += __shfl_xor(eacc0, bit);
        eacc1 += __shfl_xor(eacc1, bit);
        eacc2 += __shfl_xor(eacc2, bit);
        eacc3 += __shfl_xor(eacc3, bit);
    }
    if (lane < 8) {
        #pragma unroll
        for (int i = 0; i < 8; ++i)
            sacc[w][lane * 8 + i] = nacc[i];
    }
    if (lane < 4) {
        sacc[w][NODE_IN + lane * 4 + 0] = eacc0;
        sacc[w][NODE_IN + lane * 4 + 1] = eacc1;
        sacc[w][NODE_IN + lane * 4 + 2] = eacc2;
        sacc[w][NODE_IN + lane * 4 + 3] = eacc3;
    }
    __syncthreads();
    if (t < ACC_W) {
        float s = 0.f;
        #pragma unroll
        for (int w2 = 0; w2 < 16; ++w2) s += sacc[w2][t];
        accRow[t] = s;
    }
    __syncthreads();

    const float cntf = (float)cnt;
    float mr = 0.f;
    if (t < 96) {
        float m2 = 0.f;
        for (int k = 0; k < NODE_IN; ++k) m2 = fmaf(accRow[k], Wm[k * NODE_OUT + t], m2);
        mr = m2 + cntf * bm[t];
    } else if (t < 160) {
        const int j = t - 96;
        float m2 = 0.f;
        for (int k = 0; k < EDGE_IN; ++k) m2 = fmaf(accRow[NODE_IN + k], We[k * EDGE_OUT + j], m2);
        mr = m2 + cntf * be[j];
    }

    red[t] = (t < 160) ? mr : -1e30f;
    __syncthreads();
    for (int st = 512; st > 0; st >>= 1) {
        if (t < st) red[t] = fmaxf(red[t], red[t + st]);
        __syncthreads();
    }
    const float mx = red[0];
    __syncthreads();
    const float evx = (t < 160) ? expf(mr - mx) : 0.f;
    red[t] = evx;
    __syncthreads();
    for (int st = 512; st > 0; st >>= 1) {
        if (t < st) red[t] += red[t + st];
        __syncthreads();
    }
    if (t < 160) xbuf[(size_t)g * XDIM + t] = evx / red[0];
}

// ---------------- K5-K7: FFN, col-tiled + split-K ------------------------------
template<int NO>
__global__ __launch_bounds__(1024) void ffn_tile(
    const float* __restrict__ X, const float* __restrict__ W,
    const float* __restrict__ bias, float* __restrict__ Y,
    int Ni, int doRelu)
{
    __shared__ float part[7][4][128];   // 14 KB
    const int t = threadIdx.x;
    const int col = t & 127;
    const int ks = __builtin_amdgcn_readfirstlane(t >> 7);  // 0..7
    const int r0 = blockIdx.x * 4;
    const int cg = blockIdx.y * 128 + col;
    const int kchunk = Ni >> 3;
    const int k0 = ks * kchunk;

    const float* __restrict__ xp0 = X + (size_t)(r0 + 0) * Ni + k0;
    const float* __restrict__ xp1 = X + (size_t)(r0 + 1) * Ni + k0;
    const float* __restrict__ xp2 = X + (size_t)(r0 + 2) * Ni + k0;
    const float* __restrict__ xp3 = X + (size_t)(r0 + 3) * Ni + k0;
    const float* __restrict__ wp  = W + (size_t)k0 * NO + cg;

    float a0 = 0.f, a1 = 0.f, a2 = 0.f, a3 = 0.f;
    for (int k = 0; k < kchunk; k += 4) {
        #pragma unroll
        for (int u = 0; u < 4; ++u) {
            const float w = wp[(size_t)(k + u) * NO];
            a0 = fmaf(xp0[k + u], w, a0);
            a1 = fmaf(xp1[k + u], w, a1);
            a2 = fmaf(xp2[k + u], w, a2);
            a3 = fmaf(xp3[k + u], w, a3);
        }
    }
    if (ks > 0) {
        part[ks - 1][0][col] = a0; part[ks - 1][1][col] = a1;
        part[ks - 1][2][col] = a2; part[ks - 1][3][col] = a3;
    }
    __syncthreads();
    if (ks == 0) {
        #pragma unroll
        for (int qd = 0; qd < 7; ++qd) {
            a0 += part[qd][0][col]; a1 += part[qd][1][col];
            a2 += part[qd][2][col]; a3 += part[qd][3][col];
        }
        const float bv = bias[cg];
        float o0 = a0 + bv, o1 = a1 + bv, o2 = a2 + bv, o3 = a3 + bv;
        if (doRelu) {
            o0 = fmaxf(o0, 0.f); o1 = fmaxf(o1, 0.f);
            o2 = fmaxf(o2, 0.f); o3 = fmaxf(o3, 0.f);
        }
        Y[(size_t)(r0 + 0) * NO + cg] = o0;
        Y[(size_t)(r0 + 1) * NO + cg] = o1;
        Y[(size_t)(r0 + 2) * NO + cg] = o2;
        Y[(size_t)(r0 + 3) * NO + cg] = o3;
    }
}

extern "C" void kernel_launch(void* const* d_in, const int* in_sizes, int n_in,
                              void* d_out, int out_size, void* d_ws, size_t ws_size,
                              hipStream_t stream)
{
    const float* node_feats = (const float*)d_in[0];
    const float* edge_feats = (const float*)d_in[1];
    const float* fpv        = (const float*)d_in[2];
    const int*   src        = (const int*)d_in[3];
    const int*   dst        = (const int*)d_in[4];
    const int*   gids       = (const int*)d_in[5];
    const float* Wm  = (const float*)d_in[6];
    const float* bm  = (const float*)d_in[7];
    const float* We  = (const float*)d_in[8];
    const float* be  = (const float*)d_in[9];
    const float* Wf  = (const float*)d_in[10];
    const float* bf  = (const float*)d_in[11];
    const float* gam = (const float*)d_in[12];
    const float* bet = (const float*)d_in[13];
    const float* mu  = (const float*)d_in[14];
    const float* var = (const float*)d_in[15];
    const float* W0  = (const float*)d_in[16];
    const float* b0  = (const float*)d_in[17];
    const float* W1  = (const float*)d_in[18];
    const float* b1  = (const float*)d_in[19];
    const float* W2  = (const float*)d_in[20];
    const float* b2  = (const float*)d_in[21];
    const int E = in_sizes[3];
    const int nfTot = in_sizes[0];        // N * NODE_IN
    const int nblk = (E + HB - 1) / HB;   // 489 for E=500000 (must be <= 512)
    const int ncv = (nfTot / 8 + 1023) / 1024;   // conversion blocks

    // workspace layout (xbuf first: 500*288*4 B, 8B-aligned)
    float* xbuf  = (float*)d_ws;                          // [500][288]
    int2*  sp    = (int2*)(xbuf + (size_t)NB * XDIM);     // [E] (src, eid)
    int*   gkey  = (int*)(sp + E);                         // [E]
    int*   pbhT  = gkey + E;                               // [NB][NBLKP]
    int*   pcs   = pbhT + (size_t)NB * NBLKP;              // [nblk][NB]
    int*   gsum  = pcs + (size_t)nblk * NB;                // [NB]
    int*   offs  = gsum + NB;                              // [NB]
    float* pfp   = (float*)(offs + NB);                    // [4][500][128]
    float* h1    = pfp + (size_t)4 * NB * FPE;             // [500][512]
    float* h2    = h1 + (size_t)NB * 512;                  // [500][512]
    unsigned short* nfb = (unsigned short*)(h2 + (size_t)NB * 512);  // [N][64] bf16

    hipLaunchKernelGGL(hist_fp_kernel, dim3(nblk + NB + ncv), dim3(1024), 0, stream,
                       dst, gids, gkey, pbhT, nblk,
                       fpv, Wf, pfp, node_feats, nfb, nfTot, E);
    hipLaunchKernelGGL(colscan_kernel, dim3(NB), dim3(512), 0, stream,
                       pbhT, pcs, gsum, nblk,
                       pfp, bf, gam, bet, mu, var, xbuf);
    hipLaunchKernelGGL(scatter2_kernel, dim3(nblk), dim3(1024), 0, stream,
                       gkey, src, pcs, gsum, sp, offs, E);
    hipLaunchKernelGGL(graph_accum, dim3(NB), dim3(1024), 0, stream,
                       sp, nfb, edge_feats, offs, gsum,
                       Wm, bm, We, be, xbuf, E);
    hipLaunchKernelGGL((ffn_tile<512>), dim3(NB / 4, 4), dim3(1024), 0, stream,
                       xbuf, W0, b0, h1, XDIM, 1);
    hipLaunchKernelGGL((ffn_tile<512>), dim3(NB / 4, 4), dim3(1024), 0, stream,
                       h1, W1, b1, h2, 512, 1);
    hipLaunchKernelGGL((ffn_tile<256>), dim3(NB / 4, 2), dim3(1024), 0, stream,
                       h2, W2, b2, (float*)d_out, 512, 0);
}